// Round 3
// baseline (647.256 us; speedup 1.0000x reference)
//
#include <hip/hip_runtime.h>
#include <hip/hip_bf16.h>
#include <stdint.h>

#define K_TOT 4096
#define N_TOT 11008
#define M_TOT 256
#define BM 128
#define BN 64
#define WST 72   // padded LDS row stride in ushorts (144B = 16B-aligned, 2-way-free banks)

using bf16x8 = __attribute__((ext_vector_type(8))) short;
using f32x4  = __attribute__((ext_vector_type(4))) float;

// ---------- prep: fp32 -> bf16 (RNE) for the activation ----------
__global__ void cvt_a_bf16(const float* __restrict__ in, uint32_t* __restrict__ out) {
    int i = blockIdx.x * blockDim.x + threadIdx.x;       // one float4 per thread
    const float4 v = ((const float4*)in)[i];
    uint32_t a = __float_as_uint(v.x), b = __float_as_uint(v.y),
             c = __float_as_uint(v.z), d = __float_as_uint(v.w);
    a += 0x7FFFu + ((a >> 16) & 1u);
    b += 0x7FFFu + ((b >> 16) & 1u);
    c += 0x7FFFu + ((c >> 16) & 1u);
    d += 0x7FFFu + ((d >> 16) & 1u);
    uint2 o;
    o.x = (a >> 16) | (b & 0xFFFF0000u);
    o.y = (c >> 16) | (d & 0xFFFF0000u);
    ((uint2*)out)[i] = o;
}

// ---------- dequant 16 fp32 -> 16 bf16 packed into 8 dwords ----------
__device__ __forceinline__ void dequant16(const float4 w[4], float rs, float zp, float sc,
                                          uint32_t o[8]) {
    float f[16];
#pragma unroll
    for (int j = 0; j < 4; ++j) {
        f[4 * j + 0] = w[j].x; f[4 * j + 1] = w[j].y;
        f[4 * j + 2] = w[j].z; f[4 * j + 3] = w[j].w;
    }
    uint32_t u[16];
#pragma unroll
    for (int i = 0; i < 16; ++i) {
        float q = rintf(f[i] * rs) + zp;          // round-half-even, matches jnp.round
        q = fminf(fmaxf(q, 0.0f), 15.0f);         // maxq = 15 (fixed by reference)
        float dq = (q - zp) * sc;
        uint32_t b = __float_as_uint(dq);
        u[i] = b + 0x7FFFu + ((b >> 16) & 1u);    // bf16 RNE in high 16 bits
    }
#pragma unroll
    for (int i = 0; i < 8; ++i)
        o[i] = (u[2 * i] >> 16) | (u[2 * i + 1] & 0xFFFF0000u);
}

__device__ __forceinline__ void compute_step(f32x4 acc[4][2], const uint16_t* const Ap[4],
                                             const uint16_t (*sw)[WST], int kt, int wn, int lane) {
    const int koff = kt * 64;
#pragma unroll
    for (int s = 0; s < 2; ++s) {
        bf16x8 a[4], b[2];
#pragma unroll
        for (int mi = 0; mi < 4; ++mi)
            a[mi] = *(const bf16x8*)(Ap[mi] + koff + s * 32);
#pragma unroll
        for (int ni = 0; ni < 2; ++ni)
            b[ni] = *(const bf16x8*)&sw[wn + ni * 16 + (lane & 15)][s * 32 + (lane >> 4) * 8];
#pragma unroll
        for (int mi = 0; mi < 4; ++mi)
#pragma unroll
            for (int ni = 0; ni < 2; ++ni)
                acc[mi][ni] = __builtin_amdgcn_mfma_f32_16x16x32_bf16(a[mi], b[ni], acc[mi][ni], 0, 0, 0);
    }
}

// ---------- fused dequant + GEMM over a K-chunk, writes fp32 partials ----------
// launch_bounds(256,8): VGPR cap 64 -> up to 8 blocks/CU (LDS 18.4KB*8 = 147KB <= 160KB)
__global__ __launch_bounds__(256, 8)
void wql_gemm(const uint16_t* __restrict__ A,      // bf16 [256][4096]
              const float* __restrict__ W,         // fp32 [11008][4096]
              const float* __restrict__ scale,
              const float* __restrict__ zero,
              float* __restrict__ P,               // fp32 [KS][256][11008]
              int kloc) {                          // K-chunk length (multiple of 128)
    __shared__ uint16_t sW[2][BN][WST];            // 18.4 KB, double-buffered W tile (bf16)

    const int tid  = threadIdx.x;
    const int lane = tid & 63;
    const int wv   = tid >> 6;
    const int wm   = (wv & 1) * 64;
    const int wn   = (wv >> 1) * 32;
    const int m0   = blockIdx.x * BM;
    const int n0   = blockIdx.y * BN;
    const int k0   = blockIdx.z * kloc;
    const int nkt  = kloc / 64;

    // --- W staging role: thread owns one (row, 16-float k-segment) slot ---
    const int nloc = tid >> 2;                     // 0..63
    const int kseg = tid & 3;                      // 0..3
    const int wrow = n0 + nloc;
    const float* Wp = W + (size_t)wrow * K_TOT + k0 + kseg * 16;
    const float sc = scale[wrow];
    const float zp = zero[wrow];
    const float rs = 1.0f / sc;
    uint16_t* sdst0 = &sW[0][nloc][kseg * 16];
    uint16_t* sdst1 = &sW[1][nloc][kseg * 16];

    // --- A fragment base pointers (direct-from-global, L2/LLC-resident) ---
    const uint16_t* Ap[4];
#pragma unroll
    for (int mi = 0; mi < 4; ++mi)
        Ap[mi] = A + (size_t)(m0 + wm + mi * 16 + (lane & 15)) * K_TOT + k0 + (lane >> 4) * 8;

    f32x4 acc[4][2];
#pragma unroll
    for (int mi = 0; mi < 4; ++mi)
#pragma unroll
        for (int ni = 0; ni < 2; ++ni)
            acc[mi][ni] = (f32x4){0.f, 0.f, 0.f, 0.f};

    float4 bank0[4], bank1[4];

    // --- prologue: W(0) -> sW[0]; W(1) -> bank1 ---
#pragma unroll
    for (int j = 0; j < 4; ++j) bank0[j] = ((const float4*)Wp)[j];
    {
        uint32_t o[8];
        dequant16(bank0, rs, zp, sc, o);
        ((uint4*)sdst0)[0] = make_uint4(o[0], o[1], o[2], o[3]);
        ((uint4*)sdst0)[1] = make_uint4(o[4], o[5], o[6], o[7]);
    }
#pragma unroll
    for (int j = 0; j < 4; ++j) bank1[j] = ((const float4*)(Wp + 64))[j];
    __syncthreads();

    for (int kt = 0; kt < nkt; kt += 2) {
        // ---- even phase ----
        // 1) compute on sW[0]: A-loads issue with ZERO older vmem outstanding
        //    (previous barrier drained everything) -> A waits never touch W.
        compute_step(acc, Ap, sW[0], kt, wn, lane);
        // 2) issue W prefetch for kt+2 (newest vmem; nothing waits on it until
        //    the barrier, which has the dequant VALU phase as cover).
        if (kt + 2 < nkt) {
            const float4* p = (const float4*)(Wp + (size_t)(kt + 2) * 64);
#pragma unroll
            for (int j = 0; j < 4; ++j) bank0[j] = p[j];
        }
        // 3) dequant bank1 (kt+1 data, already resident) -> sW[1]
        {
            uint32_t o[8];
            dequant16(bank1, rs, zp, sc, o);
            ((uint4*)sdst1)[0] = make_uint4(o[0], o[1], o[2], o[3]);
            ((uint4*)sdst1)[1] = make_uint4(o[4], o[5], o[6], o[7]);
        }
        __syncthreads();

        // ---- odd phase (mirror) ----
        compute_step(acc, Ap, sW[1], kt + 1, wn, lane);
        if (kt + 3 < nkt) {
            const float4* p = (const float4*)(Wp + (size_t)(kt + 3) * 64);
#pragma unroll
            for (int j = 0; j < 4; ++j) bank1[j] = p[j];
        }
        if (kt + 2 < nkt) {
            uint32_t o[8];
            dequant16(bank0, rs, zp, sc, o);
            ((uint4*)sdst0)[0] = make_uint4(o[0], o[1], o[2], o[3]);
            ((uint4*)sdst0)[1] = make_uint4(o[4], o[5], o[6], o[7]);
        }
        __syncthreads();
    }

    // --- epilogue: store fp32 partial (no bias here) ---
    float* Pb = P + (size_t)blockIdx.z * M_TOT * N_TOT;
    const int colbase = n0 + wn + (lane & 15);
    const int rbase = m0 + wm + ((lane >> 4) << 2);
#pragma unroll
    for (int mi = 0; mi < 4; ++mi) {
#pragma unroll
        for (int ni = 0; ni < 2; ++ni) {
            const int col = colbase + ni * 16;
#pragma unroll
            for (int r = 0; r < 4; ++r) {
                const int row = rbase + mi * 16 + r;
                Pb[(size_t)row * N_TOT + col] = acc[mi][ni][r];
            }
        }
    }
}

// ---------- reduce KS partial slices + bias -> out (float4 per thread) ----------
__global__ void reduce_bias(const float* __restrict__ P, const float* __restrict__ bias,
                            float* __restrict__ out, int ks) {
    const int i4 = blockIdx.x * blockDim.x + threadIdx.x;   // float4 index
    const size_t tot4 = (size_t)M_TOT * N_TOT / 4;
    const int col = (int)(((size_t)i4 * 4) % N_TOT);        // rows are multiple-of-4 long
    float4 acc = ((const float4*)P)[i4];
    for (int s = 1; s < ks; ++s) {
        const float4 v = ((const float4*)P)[(size_t)s * tot4 + i4];
        acc.x += v.x; acc.y += v.y; acc.z += v.z; acc.w += v.w;
    }
    const float4 b = *(const float4*)(bias + col);
    acc.x += b.x; acc.y += b.y; acc.z += b.z; acc.w += b.w;
    ((float4*)out)[i4] = acc;
}

extern "C" void kernel_launch(void* const* d_in, const int* in_sizes, int n_in,
                              void* d_out, int out_size, void* d_ws, size_t ws_size,
                              hipStream_t stream) {
    const float* inp    = (const float*)d_in[0];
    const float* weight = (const float*)d_in[1];
    const float* bias   = (const float*)d_in[2];
    const float* scale  = (const float*)d_in[3];
    const float* zero   = (const float*)d_in[4];
    // d_in[5] = maxq scalar; fixed at 15 by the reference, hardcoded in dequant16.

    const size_t A_BYTES = (size_t)M_TOT * K_TOT * 2;       // 2 MB bf16 activation
    const size_t SLICE   = (size_t)M_TOT * N_TOT * 4;       // 11 MB fp32 partial

    uint32_t* Abf = (uint32_t*)d_ws;
    float* partial;
    int KS;
    if (ws_size >= A_BYTES + 8 * SLICE) { KS = 8; partial = (float*)((char*)d_ws + A_BYTES); }
    else if (ws_size >= A_BYTES + 4 * SLICE) { KS = 4; partial = (float*)((char*)d_ws + A_BYTES); }
    else if (ws_size >= A_BYTES + 2 * SLICE) { KS = 2; partial = (float*)((char*)d_ws + A_BYTES); }
    else { KS = 1; partial = (float*)d_out; }               // in-place: reduce adds bias only

    cvt_a_bf16<<<dim3((M_TOT * K_TOT / 4) / 256), dim3(256), 0, stream>>>(inp, Abf);

    dim3 grid(M_TOT / BM, N_TOT / BN, KS);                  // (2, 172, KS)
    wql_gemm<<<grid, dim3(256), 0, stream>>>((const uint16_t*)Abf, weight, scale, zero,
                                             partial, K_TOT / KS);

    reduce_bias<<<dim3((M_TOT * N_TOT / 4) / 256), dim3(256), 0, stream>>>(
        partial, bias, (float*)d_out, KS);
}

// Round 4
// 448.868 us; speedup vs baseline: 1.4420x; 1.4420x over previous
//
#include <hip/hip_runtime.h>
#include <hip/hip_bf16.h>
#include <stdint.h>

#define K_TOT 4096
#define N_TOT 11008
#define M_TOT 256

using bf16x8 = __attribute__((ext_vector_type(8))) short;
using f32x4  = __attribute__((ext_vector_type(4))) float;

// ---------- prep: fp32 -> bf16 (RNE) for the activation ----------
__global__ void cvt_a_bf16(const float* __restrict__ in, uint32_t* __restrict__ out) {
    int i = blockIdx.x * blockDim.x + threadIdx.x;       // one float4 per thread
    const float4 v = ((const float4*)in)[i];
    uint32_t a = __float_as_uint(v.x), b = __float_as_uint(v.y),
             c = __float_as_uint(v.z), d = __float_as_uint(v.w);
    a += 0x7FFFu + ((a >> 16) & 1u);
    b += 0x7FFFu + ((b >> 16) & 1u);
    c += 0x7FFFu + ((c >> 16) & 1u);
    d += 0x7FFFu + ((d >> 16) & 1u);
    uint2 o;
    o.x = (a >> 16) | (b & 0xFFFF0000u);
    o.y = (c >> 16) | (d & 0xFFFF0000u);
    ((uint2*)out)[i] = o;
}

// ---------- barrier-free fused dequant + GEMM ----------
// Wave = 128m x 16n, 8 m-frags of mfma_f32_16x16x32_bf16.  NO LDS, NO __syncthreads:
// W fp32 -> registers -> dequant -> B-fragment in-reg.  Block = 4 waves = 128m x 64n.
// launch_bounds(256,4): 128-unified-reg cap; working set ~105 -> no spill (R3 lesson:
// (256,8) = 64-reg cap forced catastrophic scratch spill, FETCH 181->680 MB).
template <int NKT>
__global__ __launch_bounds__(256, 4)
void wql_gemm(const uint16_t* __restrict__ A,      // bf16 [256][4096]
              const float* __restrict__ W,         // fp32 [11008][4096]
              const float* __restrict__ scale,
              const float* __restrict__ zero,
              float* __restrict__ P) {             // fp32 [KS][256][11008]
    const int tid   = threadIdx.x;
    const int lane  = tid & 63;
    const int wv    = tid >> 6;
    const int col16 = lane & 15;                   // n (and m) within a 16-strip
    const int kq    = lane >> 4;                   // k-quad: owns k-slice kq*8..kq*8+7
    const int m0    = blockIdx.x * 128;
    const int n0    = blockIdx.y * 64;
    const int k0    = blockIdx.z * (NKT * 32);

    // --- this lane's W column + quant params ---
    const int n = n0 + wv * 16 + col16;
    const float sc = scale[n];
    const float zp = zero[n];
    const float rs = 1.0f / sc;
    const float lo = -zp, hi = 15.0f - zp;         // clamp(rint(w*rs), -zp, 15-zp) == (q - zp)
    const float* Bp = W + (size_t)n * K_TOT + k0 + kq * 8;

    // --- A fragment base pointers (global, L2/L1-resident after first touch) ---
    const uint16_t* Ap[8];
#pragma unroll
    for (int mi = 0; mi < 8; ++mi)
        Ap[mi] = A + (size_t)(m0 + mi * 16 + col16) * K_TOT + k0 + kq * 8;

    f32x4 acc[8];
#pragma unroll
    for (int mi = 0; mi < 8; ++mi) acc[mi] = (f32x4){0.f, 0.f, 0.f, 0.f};

    // --- prologue: B(0) in flight ---
    float4 bn0 = ((const float4*)Bp)[0];
    float4 bn1 = ((const float4*)Bp)[1];

#pragma unroll 2
    for (int kt = 0; kt < NKT; ++kt) {
        // 1) A-loads for kt FIRST (so waiting on them never drains the B-prefetch)
        bf16x8 a[8];
#pragma unroll
        for (int mi = 0; mi < 8; ++mi)
            a[mi] = *(const bf16x8*)(Ap[mi] + kt * 32);

        // 2) current B = last iteration's prefetch; issue B(kt+1) (newest vmem)
        float4 bc0 = bn0, bc1 = bn1;
        if (kt + 1 < NKT) {
            bn0 = *(const float4*)(Bp + (size_t)(kt + 1) * 32);
            bn1 = *(const float4*)(Bp + (size_t)(kt + 1) * 32 + 4);
        }

        // 3) dequant 8 fp32 -> bf16x8 fragment (waits on bc: vmcnt(10), non-draining)
        float f[8] = {bc0.x, bc0.y, bc0.z, bc0.w, bc1.x, bc1.y, bc1.z, bc1.w};
        uint32_t u[8];
#pragma unroll
        for (int i = 0; i < 8; ++i) {
            float r = rintf(f[i] * rs);            // round-half-even == jnp.round
            r = fminf(fmaxf(r, lo), hi);           // exact: zp integral, range tiny
            const uint32_t b = __float_as_uint(r * sc);
            u[i] = b + 0x7FFFu + ((b >> 16) & 1u); // bf16 RNE in high 16 bits
        }
        uint32_t p[4];
#pragma unroll
        for (int i = 0; i < 4; ++i)
            p[i] = (u[2 * i] >> 16) | (u[2 * i + 1] & 0xFFFF0000u);
        const bf16x8 bf = *(const bf16x8*)p;

        // 4) MFMA (waits on a[]: vmcnt(2) -> B-prefetch stays in flight)
#pragma unroll
        for (int mi = 0; mi < 8; ++mi)
            acc[mi] = __builtin_amdgcn_mfma_f32_16x16x32_bf16(a[mi], bf, acc[mi], 0, 0, 0);
    }

    // --- epilogue: store fp32 partial ---
    float* Pb = P + (size_t)blockIdx.z * M_TOT * N_TOT;
    const int colg = n0 + wv * 16 + col16;
#pragma unroll
    for (int mi = 0; mi < 8; ++mi) {
        const int rbase = m0 + mi * 16 + kq * 4;
#pragma unroll
        for (int r = 0; r < 4; ++r)
            Pb[(size_t)(rbase + r) * N_TOT + colg] = acc[mi][r];
    }
}

// ---------- reduce KS partial slices + bias -> out (float4 per thread) ----------
__global__ void reduce_bias(const float* __restrict__ P, const float* __restrict__ bias,
                            float* __restrict__ out, int ks) {
    const int i4 = blockIdx.x * blockDim.x + threadIdx.x;   // float4 index
    const size_t tot4 = (size_t)M_TOT * N_TOT / 4;
    const int col = (int)(((size_t)i4 * 4) % N_TOT);        // rows are multiple-of-4 long
    float4 acc = ((const float4*)P)[i4];
    for (int s = 1; s < ks; ++s) {
        const float4 v = ((const float4*)P)[(size_t)s * tot4 + i4];
        acc.x += v.x; acc.y += v.y; acc.z += v.z; acc.w += v.w;
    }
    const float4 b = *(const float4*)(bias + col);
    acc.x += b.x; acc.y += b.y; acc.z += b.z; acc.w += b.w;
    ((float4*)out)[i4] = acc;
}

extern "C" void kernel_launch(void* const* d_in, const int* in_sizes, int n_in,
                              void* d_out, int out_size, void* d_ws, size_t ws_size,
                              hipStream_t stream) {
    const float* inp    = (const float*)d_in[0];
    const float* weight = (const float*)d_in[1];
    const float* bias   = (const float*)d_in[2];
    const float* scale  = (const float*)d_in[3];
    const float* zero   = (const float*)d_in[4];
    // d_in[5] = maxq scalar; fixed at 15 by the reference, hardcoded in dequant.

    const size_t A_BYTES = (size_t)M_TOT * K_TOT * 2;       // 2 MB bf16 activation
    const size_t SLICE   = (size_t)M_TOT * N_TOT * 4;       // 11 MB fp32 partial

    uint32_t* Abf = (uint32_t*)d_ws;

    cvt_a_bf16<<<dim3((M_TOT * K_TOT / 4) / 256), dim3(256), 0, stream>>>(inp, Abf);

    if (ws_size >= A_BYTES + 4 * SLICE) {
        // split-K = 4: kloc = 1024, NKT = 32
        float* partial = (float*)((char*)d_ws + A_BYTES);
        dim3 grid(M_TOT / 128, N_TOT / 64, 4);              // (2, 172, 4) = 1376 blocks
        wql_gemm<32><<<grid, dim3(256), 0, stream>>>((const uint16_t*)Abf, weight,
                                                     scale, zero, partial);
        reduce_bias<<<dim3((M_TOT * N_TOT / 4) / 256), dim3(256), 0, stream>>>(
            partial, bias, (float*)d_out, 4);
    } else {
        // fallback: no split-K, partials straight to d_out, reduce adds bias in place
        dim3 grid(M_TOT / 128, N_TOT / 64, 1);
        wql_gemm<128><<<grid, dim3(256), 0, stream>>>((const uint16_t*)Abf, weight,
                                                      scale, zero, (float*)d_out);
        reduce_bias<<<dim3((M_TOT * N_TOT / 4) / 256), dim3(256), 0, stream>>>(
            (float*)d_out, bias, (float*)d_out, 1);
    }
}

// Round 5
// 445.135 us; speedup vs baseline: 1.4541x; 1.0084x over previous
//
#include <hip/hip_runtime.h>
#include <hip/hip_bf16.h>
#include <stdint.h>

#define K_TOT 4096
#define N_TOT 11008
#define M_TOT 256

using bf16x8 = __attribute__((ext_vector_type(8))) short;
using f32x4  = __attribute__((ext_vector_type(4))) float;

// ---------- prep: fp32 -> bf16 (RNE) for the activation ----------
__global__ void cvt_a_bf16(const float* __restrict__ in, uint32_t* __restrict__ out) {
    int i = blockIdx.x * blockDim.x + threadIdx.x;       // one float4 per thread
    const float4 v = ((const float4*)in)[i];
    uint32_t a = __float_as_uint(v.x), b = __float_as_uint(v.y),
             c = __float_as_uint(v.z), d = __float_as_uint(v.w);
    a += 0x7FFFu + ((a >> 16) & 1u);
    b += 0x7FFFu + ((b >> 16) & 1u);
    c += 0x7FFFu + ((c >> 16) & 1u);
    d += 0x7FFFu + ((d >> 16) & 1u);
    uint2 o;
    o.x = (a >> 16) | (b & 0xFFFF0000u);
    o.y = (c >> 16) | (d & 0xFFFF0000u);
    ((uint2*)out)[i] = o;
}

// ---------- barrier-free fused dequant + GEMM ----------
// Wave = 128m x 16n, 8 m-frags of mfma_f32_16x16x32_bf16.  NO LDS, NO __syncthreads.
// REGISTER BUDGET IS THE POINT (R4 lesson): working set ~136 unified regs
// (a[8]=32, acc=32 AGPR, bn/bc=16, dequant temps ~16, 8 addr pairs ~20, misc).
//   (256,8) -> 64-cap: catastrophic scratch spill (R3, FETCH 181->680 MB).
//   (256,4) -> 128-cap: VGPR_Count=52, allocator serialized the A-load stream
//              into dependent L2 round-trips -> 3.5k cy/iter (R4).
//   (256,3) -> 170-cap: fits with margin, full ILP, 12 waves/CU.
// vmcnt is IN-ORDER: A-loads for kt are issued BEFORE B(kt+1), so the MFMA's
// wait on A never forces the newer B-prefetch to drain.
template <int NKT>
__global__ __launch_bounds__(256, 3)
void wql_gemm(const uint16_t* __restrict__ A,      // bf16 [256][4096]
              const float* __restrict__ W,         // fp32 [11008][4096]
              const float* __restrict__ scale,
              const float* __restrict__ zero,
              float* __restrict__ P) {             // fp32 [KS][256][11008]
    const int tid   = threadIdx.x;
    const int lane  = tid & 63;
    const int wv    = tid >> 6;
    const int col16 = lane & 15;                   // n (and m) within a 16-strip
    const int kq    = lane >> 4;                   // k-quad: owns k-slice kq*8..kq*8+7
    const int m0    = blockIdx.x * 128;
    const int n0    = blockIdx.y * 64;
    const int k0    = blockIdx.z * (NKT * 32);

    // --- this lane's W column + quant params ---
    const int n = n0 + wv * 16 + col16;
    const float sc = scale[n];
    const float zp = zero[n];
    const float rs = 1.0f / sc;
    const float lo = -zp, hi = 15.0f - zp;         // clamp(rint(w*rs), -zp, 15-zp) == (q - zp)
    const float* Bp = W + (size_t)n * K_TOT + k0 + kq * 8;

    // --- A fragment base pointers (global, L2-resident after first touch) ---
    const uint16_t* Ap[8];
#pragma unroll
    for (int mi = 0; mi < 8; ++mi)
        Ap[mi] = A + (size_t)(m0 + mi * 16 + col16) * K_TOT + k0 + kq * 8;

    f32x4 acc[8];
#pragma unroll
    for (int mi = 0; mi < 8; ++mi) acc[mi] = (f32x4){0.f, 0.f, 0.f, 0.f};

    // --- prologue: B(0) in flight ---
    float4 bn0 = ((const float4*)Bp)[0];
    float4 bn1 = ((const float4*)Bp)[1];

#pragma unroll 2
    for (int kt = 0; kt < NKT; ++kt) {
        // 1) A-loads for kt FIRST (older than the B-prefetch -> waiting on them
        //    never drains it; in-order vmcnt)
        bf16x8 a[8];
#pragma unroll
        for (int mi = 0; mi < 8; ++mi)
            a[mi] = *(const bf16x8*)(Ap[mi] + kt * 32);

        // 2) current B = last iteration's prefetch; issue B(kt+1) (newest vmem)
        float4 bc0 = bn0, bc1 = bn1;
        if (kt + 1 < NKT) {
            bn0 = *(const float4*)(Bp + (size_t)(kt + 1) * 32);
            bn1 = *(const float4*)(Bp + (size_t)(kt + 1) * 32 + 4);
        }

        // 3) dequant 8 fp32 -> bf16x8 fragment (waits on bc only)
        float f[8] = {bc0.x, bc0.y, bc0.z, bc0.w, bc1.x, bc1.y, bc1.z, bc1.w};
        uint32_t u[8];
#pragma unroll
        for (int i = 0; i < 8; ++i) {
            float r = rintf(f[i] * rs);            // round-half-even == jnp.round
            r = fminf(fmaxf(r, lo), hi);           // exact: zp integral, range tiny
            const uint32_t b = __float_as_uint(r * sc);
            u[i] = b + 0x7FFFu + ((b >> 16) & 1u); // bf16 RNE in high 16 bits
        }
        uint32_t p[4];
#pragma unroll
        for (int i = 0; i < 4; ++i)
            p[i] = (u[2 * i] >> 16) | (u[2 * i + 1] & 0xFFFF0000u);
        const bf16x8 bf = *(const bf16x8*)p;

        // 4) MFMA (waits vmcnt(2): all A done, B-prefetch stays in flight)
#pragma unroll
        for (int mi = 0; mi < 8; ++mi)
            acc[mi] = __builtin_amdgcn_mfma_f32_16x16x32_bf16(a[mi], bf, acc[mi], 0, 0, 0);
    }

    // --- epilogue: store fp32 partial ---
    float* Pb = P + (size_t)blockIdx.z * M_TOT * N_TOT;
    const int colg = n0 + wv * 16 + col16;
#pragma unroll
    for (int mi = 0; mi < 8; ++mi) {
        const int rbase = m0 + mi * 16 + kq * 4;
#pragma unroll
        for (int r = 0; r < 4; ++r)
            Pb[(size_t)(rbase + r) * N_TOT + colg] = acc[mi][r];
    }
}

// ---------- reduce KS partial slices + bias -> out (float4 per thread) ----------
__global__ void reduce_bias(const float* __restrict__ P, const float* __restrict__ bias,
                            float* __restrict__ out, int ks) {
    const int i4 = blockIdx.x * blockDim.x + threadIdx.x;   // float4 index
    const size_t tot4 = (size_t)M_TOT * N_TOT / 4;
    const int col = (int)(((size_t)i4 * 4) % N_TOT);        // rows are multiple-of-4 long
    float4 acc = ((const float4*)P)[i4];
    for (int s = 1; s < ks; ++s) {
        const float4 v = ((const float4*)P)[(size_t)s * tot4 + i4];
        acc.x += v.x; acc.y += v.y; acc.z += v.z; acc.w += v.w;
    }
    const float4 b = *(const float4*)(bias + col);
    acc.x += b.x; acc.y += b.y; acc.z += b.z; acc.w += b.w;
    ((float4*)out)[i4] = acc;
}

extern "C" void kernel_launch(void* const* d_in, const int* in_sizes, int n_in,
                              void* d_out, int out_size, void* d_ws, size_t ws_size,
                              hipStream_t stream) {
    const float* inp    = (const float*)d_in[0];
    const float* weight = (const float*)d_in[1];
    const float* bias   = (const float*)d_in[2];
    const float* scale  = (const float*)d_in[3];
    const float* zero   = (const float*)d_in[4];
    // d_in[5] = maxq scalar; fixed at 15 by the reference, hardcoded in dequant.

    const size_t A_BYTES = (size_t)M_TOT * K_TOT * 2;       // 2 MB bf16 activation
    const size_t SLICE   = (size_t)M_TOT * N_TOT * 4;       // 11 MB fp32 partial

    uint32_t* Abf = (uint32_t*)d_ws;

    cvt_a_bf16<<<dim3((M_TOT * K_TOT / 4) / 256), dim3(256), 0, stream>>>(inp, Abf);

    if (ws_size >= A_BYTES + 4 * SLICE) {
        // split-K = 4: kloc = 1024, NKT = 32
        float* partial = (float*)((char*)d_ws + A_BYTES);
        dim3 grid(M_TOT / 128, N_TOT / 64, 4);              // (2, 172, 4) = 1376 blocks
        wql_gemm<32><<<grid, dim3(256), 0, stream>>>((const uint16_t*)Abf, weight,
                                                     scale, zero, partial);
        reduce_bias<<<dim3((M_TOT * N_TOT / 4) / 256), dim3(256), 0, stream>>>(
            partial, bias, (float*)d_out, 4);
    } else {
        // fallback: no split-K, partials straight to d_out, reduce adds bias in place
        dim3 grid(M_TOT / 128, N_TOT / 64, 1);
        wql_gemm<128><<<grid, dim3(256), 0, stream>>>((const uint16_t*)Abf, weight,
                                                      scale, zero, (float*)d_out);
        reduce_bias<<<dim3((M_TOT * N_TOT / 4) / 256), dim3(256), 0, stream>>>(
            (float*)d_out, bias, (float*)d_out, 1);
    }
}

// Round 6
// 372.263 us; speedup vs baseline: 1.7387x; 1.1958x over previous
//
#include <hip/hip_runtime.h>
#include <hip/hip_bf16.h>
#include <stdint.h>

#define K_TOT 4096
#define N_TOT 11008
#define M_TOT 256

using bf16x8 = __attribute__((ext_vector_type(8))) short;
using f32x4  = __attribute__((ext_vector_type(4))) float;

// ---------- prep: fp32 -> bf16 (RNE), k-tile-major layout ----------
// Output layout: Abf[kt][m][kk]  (kt = k/32, m in [0,256), kk = k%32), i.e. one
// 16 KB slab per 32-deep k-tile.  A wave's 8 MFMA fragments for a given kt then
// live inside two 4 KB windows -> 2 base pointers + 13-bit immediate offsets.
__global__ void cvt_a_bf16(const float* __restrict__ in, uint16_t* __restrict__ out) {
    const int i = blockIdx.x * blockDim.x + threadIdx.x;   // one float4 (m, k..k+3)
    const int m  = i >> 10;                                // K/4 = 1024 float4 per row
    const int k  = (i & 1023) * 4;
    const int kt = k >> 5;
    const int kk = k & 31;
    const float4 v = ((const float4*)in)[i];
    uint32_t a = __float_as_uint(v.x), b = __float_as_uint(v.y),
             c = __float_as_uint(v.z), d = __float_as_uint(v.w);
    a += 0x7FFFu + ((a >> 16) & 1u);
    b += 0x7FFFu + ((b >> 16) & 1u);
    c += 0x7FFFu + ((c >> 16) & 1u);
    d += 0x7FFFu + ((d >> 16) & 1u);
    uint2 o;
    o.x = (a >> 16) | (b & 0xFFFF0000u);
    o.y = (c >> 16) | (d & 0xFFFF0000u);
    *(uint2*)((char*)out + (size_t)kt * 16384 + m * 64 + kk * 2) = o;
}

// ---------- barrier-free fused dequant + GEMM ----------
// Wave = 128m x 16n, 8 m-frags of mfma_f32_16x16x32_bf16.  NO LDS, NO barriers.
// REGISTER LESSONS:
//   R3 (256,8): 64-reg cap -> scratch spill, FETCH 181->680 MB.
//   R4 (256,4) / R5 (256,3): identical VGPR=52 -> launch_bounds' 2nd arg is a
//     MIN-occupancy floor; it can never RAISE the register budget.  The default
//     scheduler targets high occupancy and serialized the A-load stream.
//   R6: amdgpu_waves_per_eu(2,3) -- max=3 caps the scheduler's occupancy target,
//     raising its pressure limit to ~170 regs -> a[8] co-resident, full MLP.
// vmcnt is IN-ORDER: A(kt) issued before B(kt+2); MFMA's wait on A leaves the
// two in-flight B stages untouched.  B prefetch depth = 2 (~740cy > HBM 900-ish).
template <int NKT>
__global__ __attribute__((amdgpu_flat_work_group_size(256, 256), amdgpu_waves_per_eu(2, 3)))
void wql_gemm(const uint16_t* __restrict__ A,      // bf16, k-tile-major (see cvt)
              const float* __restrict__ W,         // fp32 [11008][4096]
              const float* __restrict__ scale,
              const float* __restrict__ zero,
              float* __restrict__ P) {             // fp32 [KS][256][11008]
    const int tid   = threadIdx.x;
    const int lane  = tid & 63;
    const int wv    = tid >> 6;
    const int col16 = lane & 15;                   // n (and m) within a 16-strip
    const int kq    = lane >> 4;                   // k-quad: owns k-slice kq*8..kq*8+7
    const int m0    = blockIdx.x * 128;
    const int n0    = blockIdx.y * 64;

    // --- this lane's W column + quant params ---
    const int n = n0 + wv * 16 + col16;
    const float sc = scale[n];
    const float zp = zero[n];
    const float rs = 1.0f / sc;
    const float lo = -zp, hi = 15.0f - zp;         // s*clamp(rint(w/s),-z,15-z) == s*(q-z)
    const float* Bp = W + (size_t)n * K_TOT + blockIdx.z * (NKT * 32) + kq * 8;

    // --- A fragment bases (k-tile-major): frag mi @ Ap0 + kt*8192 + mi*512 elems ---
    const uint16_t* Achunk = A + (size_t)blockIdx.z * NKT * 8192;
    const uint16_t* Ap0 = Achunk + (m0 + col16) * 32 + kq * 8;       // frags 0..3
    const uint16_t* Ap4 = Ap0 + 4 * 512;                             // frags 4..7

    f32x4 acc[8];
#pragma unroll
    for (int mi = 0; mi < 8; ++mi) acc[mi] = (f32x4){0.f, 0.f, 0.f, 0.f};

    // --- prologue: B(0), B(1) in flight ---
    float4 p0a = *(const float4*)(Bp);
    float4 p0b = *(const float4*)(Bp + 4);
    float4 p1a = *(const float4*)(Bp + 32);
    float4 p1b = *(const float4*)(Bp + 36);

#pragma unroll 2
    for (int kt = 0; kt < NKT; ++kt) {
        // 1) A-loads for kt (batched; older than the new B-prefetch)
        bf16x8 a[8];
#pragma unroll
        for (int mi = 0; mi < 4; ++mi) {
            a[mi]     = *(const bf16x8*)(Ap0 + kt * 8192 + mi * 512);
            a[mi + 4] = *(const bf16x8*)(Ap4 + kt * 8192 + mi * 512);
        }

        // 2) rotate B pipeline; issue B(kt+2) (newest vmem)
        const float4 c0 = p0a, c1 = p0b;           // B(kt), issued 2 iters ago
        p0a = p1a; p0b = p1b;
        if (kt + 2 < NKT) {
            p1a = *(const float4*)(Bp + (size_t)(kt + 2) * 32);
            p1b = *(const float4*)(Bp + (size_t)(kt + 2) * 32 + 4);
        }

        // 3) dequant 8 fp32 -> bf16x8 fragment (waits only on the old B(kt))
        float f[8] = {c0.x, c0.y, c0.z, c0.w, c1.x, c1.y, c1.z, c1.w};
        uint32_t u[8];
#pragma unroll
        for (int i = 0; i < 8; ++i) {
            float r = rintf(f[i] * rs);            // round-half-even == jnp.round
            r = fminf(fmaxf(r, lo), hi);           // exact: zp integral
            const uint32_t b = __float_as_uint(r * sc);
            u[i] = b + 0x7FFFu + ((b >> 16) & 1u); // bf16 RNE in high 16 bits
        }
        uint32_t p[4];
#pragma unroll
        for (int i = 0; i < 4; ++i)
            p[i] = (u[2 * i] >> 16) | (u[2 * i + 1] & 0xFFFF0000u);
        const bf16x8 bf = *(const bf16x8*)p;

        // 4) MFMA (waits vmcnt(2): all A done, B(kt+1),B(kt+2) stay in flight)
#pragma unroll
        for (int mi = 0; mi < 8; ++mi)
            acc[mi] = __builtin_amdgcn_mfma_f32_16x16x32_bf16(a[mi], bf, acc[mi], 0, 0, 0);
    }

    // --- epilogue: store fp32 partial ---
    float* Pb = P + (size_t)blockIdx.z * M_TOT * N_TOT;
    const int colg = n0 + wv * 16 + col16;
#pragma unroll
    for (int mi = 0; mi < 8; ++mi) {
        const int rbase = m0 + mi * 16 + kq * 4;
#pragma unroll
        for (int r = 0; r < 4; ++r)
            Pb[(size_t)(rbase + r) * N_TOT + colg] = acc[mi][r];
    }
}

// ---------- reduce KS partial slices + bias -> out (float4 per thread) ----------
__global__ void reduce_bias(const float* __restrict__ P, const float* __restrict__ bias,
                            float* __restrict__ out, int ks) {
    const int i4 = blockIdx.x * blockDim.x + threadIdx.x;   // float4 index
    const size_t tot4 = (size_t)M_TOT * N_TOT / 4;
    const int col = (int)(((size_t)i4 * 4) % N_TOT);        // rows are multiple-of-4 long
    float4 acc = ((const float4*)P)[i4];
    for (int s = 1; s < ks; ++s) {
        const float4 v = ((const float4*)P)[(size_t)s * tot4 + i4];
        acc.x += v.x; acc.y += v.y; acc.z += v.z; acc.w += v.w;
    }
    const float4 b = *(const float4*)(bias + col);
    acc.x += b.x; acc.y += b.y; acc.z += b.z; acc.w += b.w;
    ((float4*)out)[i4] = acc;
}

extern "C" void kernel_launch(void* const* d_in, const int* in_sizes, int n_in,
                              void* d_out, int out_size, void* d_ws, size_t ws_size,
                              hipStream_t stream) {
    const float* inp    = (const float*)d_in[0];
    const float* weight = (const float*)d_in[1];
    const float* bias   = (const float*)d_in[2];
    const float* scale  = (const float*)d_in[3];
    const float* zero   = (const float*)d_in[4];
    // d_in[5] = maxq scalar; fixed at 15 by the reference, hardcoded in dequant.

    const size_t A_BYTES = (size_t)M_TOT * K_TOT * 2;       // 2 MB bf16 activation
    const size_t SLICE   = (size_t)M_TOT * N_TOT * 4;       // 11 MB fp32 partial

    uint16_t* Abf = (uint16_t*)d_ws;

    cvt_a_bf16<<<dim3((M_TOT * K_TOT / 4) / 256), dim3(256), 0, stream>>>(inp, Abf);

    if (ws_size >= A_BYTES + 4 * SLICE) {
        // split-K = 4: kloc = 1024, NKT = 32
        float* partial = (float*)((char*)d_ws + A_BYTES);
        dim3 grid(M_TOT / 128, N_TOT / 64, 4);              // (2, 172, 4) = 1376 blocks
        wql_gemm<32><<<grid, dim3(256), 0, stream>>>(Abf, weight, scale, zero, partial);
        reduce_bias<<<dim3((M_TOT * N_TOT / 4) / 256), dim3(256), 0, stream>>>(
            partial, bias, (float*)d_out, 4);
    } else {
        // fallback: no split-K, partials straight to d_out, reduce adds bias in place
        dim3 grid(M_TOT / 128, N_TOT / 64, 1);
        wql_gemm<128><<<grid, dim3(256), 0, stream>>>(Abf, weight, scale, zero, (float*)d_out);
        reduce_bias<<<dim3((M_TOT * N_TOT / 4) / 256), dim3(256), 0, stream>>>(
            (float*)d_out, bias, (float*)d_out, 1);
    }
}